// Round 3
// baseline (2039.107 us; speedup 1.0000x reference)
//
#include <hip/hip_runtime.h>
#include <hip/hip_bf16.h>
#include <stdint.h>

// Problem constants (fixed by the reference)
#define N_NODES 50000
#define N_EDGES 1600000
#define IN_DIM  1024
#define HID     2048
#define OUTC    3
#define M_PAD   50048   // 391 * 128 — M padded to GEMM tile
#define BN_EPS  1e-5f

#define SCAN_CH 512
#define NCH     98      // ceil(50000/512)

// agg1: feature panels sized for per-XCD L2 residency.
// 32 feats * 50048 nodes * 2B = 3.2 MB < 4 MB L2 per XCD.
#define NPAN    32                        // 1024 / 32 panels
#define PF      32                        // feats per panel
#define PSTRIDE ((size_t)M_PAD * PF)      // elems per panel (3.2 MB)
#define NGRP    782                       // node-groups of 64: 50048/64
#define NXCD    8
#define DUMMY_SRC N_NODES                 // padding edges point at zero row 50000
#define E_PAD_MAX (N_EDGES + 3 * N_NODES + 64) // CSR rows padded to x4, + prefetch slack
#define DBINS   256                       // degree-sort bins (padded degree / 4)

typedef __bf16 bf16_t;
typedef __bf16 bf16x4_t __attribute__((ext_vector_type(4)));
typedef __bf16 bf16x8_t __attribute__((ext_vector_type(8)));
typedef float  f32x4_t  __attribute__((ext_vector_type(4)));
typedef int    i32x4_t  __attribute__((ext_vector_type(4)));

// async global->LDS, 16B per lane. LDS layout must be contiguous in lane order.
__device__ __forceinline__ void gl2lds16(const void* g, void* l) {
  __builtin_amdgcn_global_load_lds((const __attribute__((address_space(1))) uint32_t*)g,
                                   (__attribute__((address_space(3))) uint32_t*)l,
                                   16, 0, 0);
}

// nontemporal 16B index load (keeps the 32x-streamed csr out of the panel L2)
__device__ __forceinline__ i32x4_t nt4(const int* p) {
  return __builtin_nontemporal_load((const i32x4_t*)p);
}

// gather one node's 16B panel segment
__device__ __forceinline__ bf16x8_t gat(const bf16_t* xp, int i) {
  return *(const bf16x8_t*)(xp + ((size_t)(unsigned)i << 5));
}

// ---------- degree histograms ----------
__global__ void k_hist(const int* __restrict__ src, const int* __restrict__ dst,
                       int* out_cnt, int* in_cnt) {
  int e = blockIdx.x * 256 + threadIdx.x;
  if (e < N_EDGES) {
    atomicAdd(&out_cnt[src[e]], 1);
    atomicAdd(&in_cnt[dst[e]], 1);
  }
}

// ---------- degree norms: clip(deg,1)^-0.5 (RAW degrees) ----------
__global__ void k_norms(const int* __restrict__ out_cnt, const int* __restrict__ in_cnt,
                        float* out_norm, float* in_norm) {
  int i = blockIdx.x * 256 + threadIdx.x;
  if (i < N_NODES) {
    out_norm[i] = rsqrtf((float)max(out_cnt[i], 1));
    in_norm[i]  = rsqrtf((float)max(in_cnt[i], 1));
  }
}

// ---------- degree-sort (counting sort by padded degree) ----------
// waves of k_agg1 then see 16 equal-trip-count nodes -> no intra-wave divergence
__global__ void k_dhist(const int* __restrict__ in_cnt, int* dhist) {
  int i = blockIdx.x * 256 + threadIdx.x;
  if (i < N_NODES) {
    int b = min((in_cnt[i] + 3) >> 2, DBINS - 1);
    atomicAdd(&dhist[b], 1);
  }
}

__global__ void k_dscan(const int* __restrict__ dhist, int* doff, int* dcur) {
  if (threadIdx.x == 0 && blockIdx.x == 0) {
    int run = 0;
    for (int b = 0; b < DBINS; b++) { doff[b] = run; dcur[b] = run; run += dhist[b]; }
  }
}

__global__ void k_dscat(const int* __restrict__ in_cnt, int* dcur, int* perm) {
  int i = blockIdx.x * 256 + threadIdx.x;
  if (i < N_NODES) {
    int b = min((in_cnt[i] + 3) >> 2, DBINS - 1);
    perm[atomicAdd(&dcur[b], 1)] = i;
  }
}

// ---------- exclusive scan of PADDED in-degrees (3-phase) ----------
// rows padded to multiple of 4 so agg1's gather loop needs no masking
__global__ void k_scan1(const int* __restrict__ deg, int* incl, int* partial) {
  __shared__ int s[SCAN_CH];
  int tid = threadIdx.x;
  int i = blockIdx.x * SCAN_CH + tid;
  int v = (i < N_NODES) ? ((deg[i] + 3) & ~3) : 0;
  s[tid] = v;
  for (int off = 1; off < SCAN_CH; off <<= 1) {
    __syncthreads();
    int x = (tid >= off) ? s[tid - off] : 0;
    __syncthreads();
    s[tid] += x;
  }
  __syncthreads();
  if (i < N_NODES) incl[i] = s[tid];
  if (tid == SCAN_CH - 1) partial[blockIdx.x] = s[tid];
}

__global__ void k_scan2(const int* __restrict__ partial, int* chunk_off, int* row_ptr) {
  if (threadIdx.x == 0 && blockIdx.x == 0) {
    int run = 0;
    for (int b = 0; b < NCH; b++) { chunk_off[b] = run; run += partial[b]; }
    row_ptr[N_NODES] = run;   // == padded edge count
  }
}

__global__ void k_scan3(const int* __restrict__ deg, const int* __restrict__ incl,
                        const int* __restrict__ chunk_off, int* row_ptr, int* cursor) {
  int i = blockIdx.x * SCAN_CH + threadIdx.x;
  if (i < N_NODES) {
    int dp = (deg[i] + 3) & ~3;
    int e = chunk_off[blockIdx.x] + incl[i] - dp;
    row_ptr[i] = e;
    cursor[i]  = e;
  }
}

// ---------- CSR fill (bucket by dst); padding slots filled by k_pad ----------
__global__ void k_fill(const int* __restrict__ src, const int* __restrict__ dst,
                       int* cursor, int* csr_src) {
  int e = blockIdx.x * 256 + threadIdx.x;
  if (e < N_EDGES) {
    int p = atomicAdd(&cursor[dst[e]], 1);
    csr_src[p] = src[e];
  }
}

// ---------- fill row-padding slots with the dummy (zero) source node ----------
__global__ void k_pad(const int* __restrict__ in_cnt, const int* __restrict__ row_ptr,
                      int* csr_src) {
  int i = blockIdx.x * 256 + threadIdx.x;
  if (i < N_NODES) {
    int d = in_cnt[i], dp = (d + 3) & ~3;
    int base = row_ptr[i];
    for (int j = d; j < dp; j++) csr_src[base + j] = DUMMY_SRC;
  }
}

// ---------- convert features, panel-major: xbp[p][n][32] = bf16(in_feat*out_norm) ----------
// rows >= N_NODES (incl. the dummy row 50000) are zero
__global__ void k_conv(const float* __restrict__ in_feat, const float* __restrict__ out_norm,
                       bf16_t* __restrict__ xbp) {
  int node = blockIdx.x, t = threadIdx.x;
  int p = t >> 3, fo = (t & 7) * 4;       // panel, feat offset within panel
  bf16x4_t o;
  if (node < N_NODES) {
    float on = out_norm[node];
    float4 v = *(const float4*)(in_feat + (size_t)node * IN_DIM + p * PF + fo);
    o[0] = (bf16_t)(v.x * on); o[1] = (bf16_t)(v.y * on);
    o[2] = (bf16_t)(v.z * on); o[3] = (bf16_t)(v.w * on);
  } else {
    o[0] = (bf16_t)0.f; o[1] = (bf16_t)0.f; o[2] = (bf16_t)0.f; o[3] = (bf16_t)0.f;
  }
  *(bf16x4_t*)(xbp + (size_t)p * PSTRIDE + (size_t)node * PF + fo) = o;
}

// ---------- layer-1 aggregation: L2-resident panels + degree-sorted nodes ----------
// panel = (blockIdx.x & 7) + 8*phase keeps one 3.2 MB panel per XCD L2 (r2: FETCH
// 1.49->0.81 GB, confirmed). r2 regression fixes: (a) nodes taken via degree-sorted
// perm so a wave's 16 quads have equal trip counts; (b) indices loaded as int4 per
// lane (quad-broadcast, no shfl) and prefetched 2 iterations ahead so the ~900cy
// nt csr miss is off the critical path; (c) 8 gathers (8 KB/wave) in flight.
__global__ void __launch_bounds__(256)
k_agg1(const bf16_t* __restrict__ xbp, const int* __restrict__ row_ptr,
       const int* __restrict__ csr_src, const float* __restrict__ in_norm,
       const int* __restrict__ perm, bf16_t* __restrict__ aggb) {
  int b = blockIdx.x;
  int xcd = b & (NXCD - 1), seq = b >> 3;
  int phase = seq / NGRP, grp = seq - phase * NGRP;
  int panel = xcd + (phase << 3);
  int wv = threadIdx.x >> 6, lane = threadIdx.x & 63;
  int ch = lane >> 2, seg = lane & 3;
  int idx = grp * 64 + wv * 16 + ch;
  int node = (idx < N_NODES) ? perm[idx] : N_NODES;  // pad idx -> dummy row

  const bf16_t* xp = xbp + (size_t)panel * PSTRIDE + (seg << 3);

  int beg = 0, end = 0;
  if (node < N_NODES) { beg = row_ptr[node]; end = row_ptr[node + 1]; }

  float acc[8];
#pragma unroll
  for (int j = 0; j < 8; j++) acc[j] = 0.f;

  int e = beg;
  i32x4_t a0, b0, a1, b1;
  if (e + 8 <= end)  { a0 = nt4(csr_src + e);     b0 = nt4(csr_src + e + 4); }
  if (e + 16 <= end) { a1 = nt4(csr_src + e + 8); b1 = nt4(csr_src + e + 12); }

  for (; e + 16 <= end; e += 8) {
    bf16x8_t v0 = gat(xp, a0.x), v1 = gat(xp, a0.y), v2 = gat(xp, a0.z), v3 = gat(xp, a0.w);
    bf16x8_t v4 = gat(xp, b0.x), v5 = gat(xp, b0.y), v6 = gat(xp, b0.z), v7 = gat(xp, b0.w);
    a0 = a1; b0 = b1;
    a1 = nt4(csr_src + e + 16);   // prefetch iteration k+2 (slack-allocated; values
    b1 = nt4(csr_src + e + 20);   // only consumed if the next iteration runs)
#pragma unroll
    for (int j = 0; j < 8; j++) acc[j] += (float)v0[j];
#pragma unroll
    for (int j = 0; j < 8; j++) acc[j] += (float)v1[j];
#pragma unroll
    for (int j = 0; j < 8; j++) acc[j] += (float)v2[j];
#pragma unroll
    for (int j = 0; j < 8; j++) acc[j] += (float)v3[j];
#pragma unroll
    for (int j = 0; j < 8; j++) acc[j] += (float)v4[j];
#pragma unroll
    for (int j = 0; j < 8; j++) acc[j] += (float)v5[j];
#pragma unroll
    for (int j = 0; j < 8; j++) acc[j] += (float)v6[j];
#pragma unroll
    for (int j = 0; j < 8; j++) acc[j] += (float)v7[j];
  }
  if (e + 8 <= end) {   // a0/b0 still hold idx[e..e+7]
    bf16x8_t v0 = gat(xp, a0.x), v1 = gat(xp, a0.y), v2 = gat(xp, a0.z), v3 = gat(xp, a0.w);
    bf16x8_t v4 = gat(xp, b0.x), v5 = gat(xp, b0.y), v6 = gat(xp, b0.z), v7 = gat(xp, b0.w);
#pragma unroll
    for (int j = 0; j < 8; j++) acc[j] += (float)v0[j];
#pragma unroll
    for (int j = 0; j < 8; j++) acc[j] += (float)v1[j];
#pragma unroll
    for (int j = 0; j < 8; j++) acc[j] += (float)v2[j];
#pragma unroll
    for (int j = 0; j < 8; j++) acc[j] += (float)v3[j];
#pragma unroll
    for (int j = 0; j < 8; j++) acc[j] += (float)v4[j];
#pragma unroll
    for (int j = 0; j < 8; j++) acc[j] += (float)v5[j];
#pragma unroll
    for (int j = 0; j < 8; j++) acc[j] += (float)v6[j];
#pragma unroll
    for (int j = 0; j < 8; j++) acc[j] += (float)v7[j];
    e += 8;
  }
  if (e + 4 <= end) {
    i32x4_t c = nt4(csr_src + e);
    bf16x8_t v0 = gat(xp, c.x), v1 = gat(xp, c.y), v2 = gat(xp, c.z), v3 = gat(xp, c.w);
#pragma unroll
    for (int j = 0; j < 8; j++) acc[j] += (float)v0[j];
#pragma unroll
    for (int j = 0; j < 8; j++) acc[j] += (float)v1[j];
#pragma unroll
    for (int j = 0; j < 8; j++) acc[j] += (float)v2[j];
#pragma unroll
    for (int j = 0; j < 8; j++) acc[j] += (float)v3[j];
  }

  float inn = (node < N_NODES) ? in_norm[node] : 0.f;
  bf16x8_t o;
#pragma unroll
  for (int j = 0; j < 8; j++) o[j] = (bf16_t)(acc[j] * inn);
  __builtin_nontemporal_store(o,
      (bf16x8_t*)(aggb + (size_t)node * IN_DIM + panel * PF + (seg << 3)));
}

// ---------- W1 [K=1024][N=2048] fp32 -> W1t [N][K] bf16, LDS-tiled transpose ----------
__global__ void k_w1t(const float* __restrict__ W1, bf16_t* __restrict__ W1t) {
  __shared__ float tile[32][33];
  int k0 = blockIdx.x * 32, n0 = blockIdx.y * 32;
  int tx = threadIdx.x & 31, ty = threadIdx.x >> 5;   // 32 x 8
#pragma unroll
  for (int r = 0; r < 32; r += 8)
    tile[ty + r][tx] = W1[(size_t)(k0 + ty + r) * HID + n0 + tx];
  __syncthreads();
#pragma unroll
  for (int r = 0; r < 32; r += 8)
    W1t[(size_t)(n0 + ty + r) * IN_DIM + k0 + tx] = (bf16_t)tile[tx][ty + r];
}

// ---------- GEMM1: h1 = relu(agg @ W1 + b1) + fused BN column stats ----------
// m97 structure: 128x128 tile, BK=32, 4 waves in 2x2, 16x16x32 MFMA, global_load_lds w=16.
__global__ void __launch_bounds__(256)
k_gemm1(const bf16_t* __restrict__ A, const bf16_t* __restrict__ Bt,
        const float* __restrict__ b1, bf16_t* __restrict__ C,
        float* __restrict__ colsum, float* __restrict__ colsq) {
  __shared__ bf16_t As[128 * 32];
  __shared__ bf16_t Bs[128 * 32];
  int t = threadIdx.x;
  const int m0 = blockIdx.y * 128, n0 = blockIdx.x * 128;

  int lrow = t >> 2, lseg = t & 3;
  const bf16_t* aG0 = A + (size_t)(m0 + lrow) * IN_DIM + lseg * 8;
  const bf16_t* aG1 = aG0 + (size_t)64 * IN_DIM;
  const bf16_t* bG0 = Bt + (size_t)(n0 + lrow) * IN_DIM + lseg * 8;
  const bf16_t* bG1 = bG0 + (size_t)64 * IN_DIM;
  bf16_t* aL0 = As + t * 8; bf16_t* aL1 = As + 2048 + t * 8;
  bf16_t* bL0 = Bs + t * 8; bf16_t* bL1 = Bs + 2048 + t * 8;

  int wv = t >> 6, ln = t & 63;
  int wm = (wv >> 1) * 64, wn = (wv & 1) * 64;
  int fr = ln & 15, fq = ln >> 4;
  const bf16_t* aF = As + (wm + fr) * 32 + fq * 8;
  const bf16_t* bF = Bs + (wn + fr) * 32 + fq * 8;

  f32x4_t acc[4][4];
#pragma unroll
  for (int i = 0; i < 4; i++)
#pragma unroll
    for (int j = 0; j < 4; j++) { acc[i][j][0]=0.f; acc[i][j][1]=0.f; acc[i][j][2]=0.f; acc[i][j][3]=0.f; }

  for (int kt = 0; kt < IN_DIM; kt += 32) {
    __syncthreads();
    gl2lds16(aG0 + kt, aL0);
    gl2lds16(aG1 + kt, aL1);
    gl2lds16(bG0 + kt, bL0);
    gl2lds16(bG1 + kt, bL1);
    __syncthreads();
    bf16x8_t af[4], bfr[4];
#pragma unroll
    for (int i = 0; i < 4; i++) af[i]  = *(const bf16x8_t*)(aF + i * 16 * 32);
#pragma unroll
    for (int j = 0; j < 4; j++) bfr[j] = *(const bf16x8_t*)(bF + j * 16 * 32);
#pragma unroll
    for (int i = 0; i < 4; i++)
#pragma unroll
      for (int j = 0; j < 4; j++)
        acc[i][j] = __builtin_amdgcn_mfma_f32_16x16x32_bf16(af[i], bfr[j], acc[i][j], 0, 0, 0);
  }

#pragma unroll
  for (int j = 0; j < 4; j++) {
    int col = n0 + wn + j * 16 + fr;
    float bias = b1[col];
    float s = 0.f, ss = 0.f;
#pragma unroll
    for (int i = 0; i < 4; i++) {
#pragma unroll
      for (int r = 0; r < 4; r++) {
        int row = m0 + wm + i * 16 + fq * 4 + r;
        float v = acc[i][j][r] + bias;
        v = v > 0.f ? v : 0.f;
        bf16_t bv = (bf16_t)v;
        __builtin_nontemporal_store(*(short*)&bv, (short*)&C[(size_t)row * HID + col]);
        if (row < N_NODES) { s += v; ss += v * v; }
      }
    }
    s  += __shfl_xor(s, 16);  s  += __shfl_xor(s, 32);
    ss += __shfl_xor(ss, 16); ss += __shfl_xor(ss, 32);
    if (fq == 0) {
      atomicAdd(&colsum[col], s);
      atomicAdd(&colsq[col], ss);
    }
  }
}

// ---------- fold BN into Wout: cw[f,o] = rs[f]*Wout[f,o]; mrs[f] = mean[f]*rs[f] ----------
__global__ void k_bnfin(const float* __restrict__ colsum, const float* __restrict__ colsq,
                        const float* __restrict__ Wout,
                        float* cw0, float* cw1, float* cw2, float* mrs) {
  int f = blockIdx.x * 256 + threadIdx.x;
  if (f < HID) {
    float mean = colsum[f] * (1.f / N_NODES);
    float var  = colsq[f] * (1.f / N_NODES) - mean * mean;
    float rs   = rsqrtf(var + BN_EPS);
    cw0[f] = rs * Wout[f * 3 + 0];
    cw1[f] = rs * Wout[f * 3 + 1];
    cw2[f] = rs * Wout[f * 3 + 2];
    mrs[f] = mean * rs;
  }
}

// ---------- ct[o] = sum_f mrs[f]*Wout[f,o] ----------
__global__ void k_ct(const float* __restrict__ mrs, const float* __restrict__ Wout, float* ct) {
  __shared__ float red[3][256];
  int tid = threadIdx.x;
  float s0 = 0.f, s1 = 0.f, s2 = 0.f;
  for (int f = tid; f < HID; f += 256) {
    float m = mrs[f];
    s0 += m * Wout[f * 3 + 0];
    s1 += m * Wout[f * 3 + 1];
    s2 += m * Wout[f * 3 + 2];
  }
  red[0][tid] = s0; red[1][tid] = s1; red[2][tid] = s2;
  __syncthreads();
  for (int off = 128; off; off >>= 1) {
    if (tid < off) {
      red[0][tid] += red[0][tid + off];
      red[1][tid] += red[1][tid + off];
      red[2][tid] += red[2][tid + off];
    }
    __syncthreads();
  }
  if (tid == 0) { ct[0] = red[0][0]; ct[1] = red[1][0]; ct[2] = red[2][0]; }
}

// ---------- t[n] = out_norm[n] * (h_bn[n] @ Wout) via cw/ct ----------
__global__ void k_tmat(const bf16_t* __restrict__ h1, const float* __restrict__ cw0,
                       const float* __restrict__ cw1, const float* __restrict__ cw2,
                       const float* __restrict__ ct, const float* __restrict__ out_norm,
                       float4* __restrict__ t4) {
  int n = blockIdx.x, tid = threadIdx.x;
  int f0 = tid * 8;
  bf16x8_t hv = *(const bf16x8_t*)(h1 + (size_t)n * HID + f0);
  float s0 = 0.f, s1 = 0.f, s2 = 0.f;
#pragma unroll
  for (int j = 0; j < 8; j++) {
    float h = (float)hv[j];
    s0 += h * cw0[f0 + j];
    s1 += h * cw1[f0 + j];
    s2 += h * cw2[f0 + j];
  }
#pragma unroll
  for (int off = 32; off; off >>= 1) {
    s0 += __shfl_down(s0, off);
    s1 += __shfl_down(s1, off);
    s2 += __shfl_down(s2, off);
  }
  __shared__ float red[3][4];
  int wv = tid >> 6, ln = tid & 63;
  if (ln == 0) { red[0][wv] = s0; red[1][wv] = s1; red[2][wv] = s2; }
  __syncthreads();
  if (tid == 0) {
    float r0 = red[0][0] + red[0][1] + red[0][2] + red[0][3];
    float r1 = red[1][0] + red[1][1] + red[1][2] + red[1][3];
    float r2 = red[2][0] + red[2][1] + red[2][2] + red[2][3];
    float on = out_norm[n];
    t4[n] = make_float4(on * (r0 - ct[0]), on * (r1 - ct[1]), on * (r2 - ct[2]), 0.f);
  }
}

// ---------- layer-2 aggregation (3 feats) + bias + softmax ----------
// padded CSR slots point at t4[DUMMY_SRC] which is zeroed
__global__ void k_out(const int* __restrict__ row_ptr, const int* __restrict__ csr_src,
                      const float4* __restrict__ t4, const float* __restrict__ in_norm,
                      const float* __restrict__ bout, float* __restrict__ out) {
  int i = blockIdx.x * 256 + threadIdx.x;
  if (i >= N_NODES) return;
  float a0 = 0.f, a1 = 0.f, a2 = 0.f;
  int beg = row_ptr[i], end = row_ptr[i + 1];
  for (int e = beg; e < end; e++) {
    float4 tv = t4[csr_src[e]];
    a0 += tv.x; a1 += tv.y; a2 += tv.z;
  }
  float inn = in_norm[i];
  float l0 = inn * a0 + bout[0];
  float l1 = inn * a1 + bout[1];
  float l2 = inn * a2 + bout[2];
  float m = fmaxf(l0, fmaxf(l1, l2));
  float e0 = expf(l0 - m), e1 = expf(l1 - m), e2 = expf(l2 - m);
  float rs = 1.f / (e0 + e1 + e2);
  out[i * 3 + 0] = e0 * rs;
  out[i * 3 + 1] = e1 * rs;
  out[i * 3 + 2] = e2 * rs;
}

extern "C" void kernel_launch(void* const* d_in, const int* in_sizes, int n_in,
                              void* d_out, int out_size, void* d_ws, size_t ws_size,
                              hipStream_t stream) {
  const float* in_feat = (const float*)d_in[0];
  const int*   src     = (const int*)d_in[1];
  const int*   dst     = (const int*)d_in[2];
  const float* W1      = (const float*)d_in[3];
  const float* b1      = (const float*)d_in[4];
  const float* Wout    = (const float*)d_in[5];
  const float* bout    = (const float*)d_in[6];
  float* out = (float*)d_out;

  char* p = (char*)d_ws;
  auto alloc = [&](size_t bytes) { char* r = p; p += (bytes + 255) & ~(size_t)255; return r; };
  bf16_t* h1      = (bf16_t*)alloc((size_t)M_PAD * HID * 2);      // 205 MB
  bf16_t* aggb    = (bf16_t*)alloc((size_t)M_PAD * IN_DIM * 2);   // 102.5 MB
  bf16_t* xbp     = (bf16_t*)alloc((size_t)NPAN * PSTRIDE * 2);   // 102.5 MB, panel-major
  bf16_t* W1t     = (bf16_t*)alloc((size_t)HID * IN_DIM * 2);     // 4 MB
  int* csr_src    = (int*)alloc((size_t)E_PAD_MAX * 4);           // 7 MB (padded + slack)
  int* row_ptr    = (int*)alloc((size_t)(N_NODES + 1) * 4);
  int* cursor     = (int*)alloc((size_t)N_NODES * 4);
  int* incl       = (int*)alloc((size_t)N_NODES * 4);
  int* partial    = (int*)alloc((size_t)NCH * 4);
  int* chunk_off  = (int*)alloc((size_t)NCH * 4);
  int* out_cnt    = (int*)alloc((size_t)N_NODES * 4);
  int* in_cnt     = (int*)alloc((size_t)N_NODES * 4);
  int* perm       = (int*)alloc((size_t)N_NODES * 4);
  int* dhist      = (int*)alloc((size_t)DBINS * 4);
  int* doff       = (int*)alloc((size_t)DBINS * 4);
  int* dcur       = (int*)alloc((size_t)DBINS * 4);
  float* out_norm = (float*)alloc((size_t)N_NODES * 4);
  float* in_norm  = (float*)alloc((size_t)N_NODES * 4);
  float* colsum   = (float*)alloc((size_t)HID * 4);
  float* colsq    = (float*)alloc((size_t)HID * 4);
  float* cw0      = (float*)alloc((size_t)HID * 4);
  float* cw1      = (float*)alloc((size_t)HID * 4);
  float* cw2      = (float*)alloc((size_t)HID * 4);
  float* mrs      = (float*)alloc((size_t)HID * 4);
  float* ct       = (float*)alloc(4 * 4);
  float4* t4      = (float4*)alloc((size_t)M_PAD * 16);

  // ws is poisoned 0xAA each call — zero what needs zeroing
  hipMemsetAsync(out_cnt, 0, (size_t)N_NODES * 4, stream);
  hipMemsetAsync(in_cnt,  0, (size_t)N_NODES * 4, stream);
  hipMemsetAsync(dhist,   0, (size_t)DBINS * 4, stream);
  hipMemsetAsync(colsum,  0, (size_t)HID * 4, stream);
  hipMemsetAsync(colsq,   0, (size_t)HID * 4, stream);
  hipMemsetAsync(t4 + N_NODES, 0, (size_t)(M_PAD - N_NODES) * 16, stream); // dummy t4 rows

  k_hist <<<(N_EDGES + 255) / 256, 256, 0, stream>>>(src, dst, out_cnt, in_cnt);
  k_norms<<<(N_NODES + 255) / 256, 256, 0, stream>>>(out_cnt, in_cnt, out_norm, in_norm);
  k_conv <<<M_PAD, 256, 0, stream>>>(in_feat, out_norm, xbp);
  k_dhist<<<(N_NODES + 255) / 256, 256, 0, stream>>>(in_cnt, dhist);
  k_dscan<<<1, 64, 0, stream>>>(dhist, doff, dcur);
  k_dscat<<<(N_NODES + 255) / 256, 256, 0, stream>>>(in_cnt, dcur, perm);
  k_scan1<<<NCH, SCAN_CH, 0, stream>>>(in_cnt, incl, partial);
  k_scan2<<<1, 64, 0, stream>>>(partial, chunk_off, row_ptr);
  k_scan3<<<NCH, SCAN_CH, 0, stream>>>(in_cnt, incl, chunk_off, row_ptr, cursor);
  k_pad  <<<(N_NODES + 255) / 256, 256, 0, stream>>>(in_cnt, row_ptr, csr_src);
  k_fill <<<(N_EDGES + 255) / 256, 256, 0, stream>>>(src, dst, cursor, csr_src);
  k_w1t  <<<dim3(IN_DIM / 32, HID / 32), 256, 0, stream>>>(W1, W1t);
  k_agg1 <<<NXCD * (NPAN / NXCD) * NGRP, 256, 0, stream>>>(xbp, row_ptr, csr_src, in_norm, perm, aggb);
  k_gemm1<<<dim3(HID / 128, M_PAD / 128), 256, 0, stream>>>(aggb, W1t, b1, h1, colsum, colsq);
  k_bnfin<<<HID / 256, 256, 0, stream>>>(colsum, colsq, Wout, cw0, cw1, cw2, mrs);
  k_ct   <<<1, 256, 0, stream>>>(mrs, Wout, ct);
  k_tmat <<<N_NODES, 256, 0, stream>>>(h1, cw0, cw1, cw2, ct, out_norm, t4);
  k_out  <<<(N_NODES + 255) / 256, 256, 0, stream>>>(row_ptr, csr_src, t4, in_norm, bout, out);
}

// Round 4
// 1491.399 us; speedup vs baseline: 1.3672x; 1.3672x over previous
//
#include <hip/hip_runtime.h>
#include <hip/hip_bf16.h>
#include <stdint.h>

// Problem constants (fixed by the reference)
#define N_NODES 50000
#define N_EDGES 1600000
#define IN_DIM  1024
#define HID     2048
#define OUTC    3
#define M_PAD   50048   // 391 * 128 — M padded to GEMM tile
#define BN_EPS  1e-5f

#define SCAN_CH 512
#define NCH     98      // ceil(50000/512)

// agg1: feature panels. 64 feats * 50048 nodes * 2B = 6.4 MB per panel.
// Per-edge slice = 128B = one full cache line (request-path friendly);
// XCD pinning gives ~60% L2 service, L3 backs the rest (102 MB total, L3-fit).
#define NPAN    16                        // 1024 / 64 panels
#define PF      64                        // feats per panel
#define PSTRIDE ((size_t)M_PAD * PF)      // elems per panel (6.4 MB)
#define NGRP4   12512                     // node-groups of 4: 50048/4
#define NXCD    8
#define DUMMY_SRC N_NODES                 // padding edges point at zero row 50000
#define E_PAD_MAX (N_EDGES + 3 * N_NODES + 64) // CSR rows padded to x4, + slack

typedef __bf16 bf16_t;
typedef __bf16 bf16x4_t __attribute__((ext_vector_type(4)));
typedef __bf16 bf16x8_t __attribute__((ext_vector_type(8)));
typedef float  f32x4_t  __attribute__((ext_vector_type(4)));

// async global->LDS, 16B per lane. LDS layout must be contiguous in lane order.
__device__ __forceinline__ void gl2lds16(const void* g, void* l) {
  __builtin_amdgcn_global_load_lds((const __attribute__((address_space(1))) uint32_t*)g,
                                   (__attribute__((address_space(3))) uint32_t*)l,
                                   16, 0, 0);
}

// ---------- degree histograms ----------
__global__ void k_hist(const int* __restrict__ src, const int* __restrict__ dst,
                       int* out_cnt, int* in_cnt) {
  int e = blockIdx.x * 256 + threadIdx.x;
  if (e < N_EDGES) {
    atomicAdd(&out_cnt[src[e]], 1);
    atomicAdd(&in_cnt[dst[e]], 1);
  }
}

// ---------- degree norms: clip(deg,1)^-0.5 (RAW degrees) ----------
__global__ void k_norms(const int* __restrict__ out_cnt, const int* __restrict__ in_cnt,
                        float* out_norm, float* in_norm) {
  int i = blockIdx.x * 256 + threadIdx.x;
  if (i < N_NODES) {
    out_norm[i] = rsqrtf((float)max(out_cnt[i], 1));
    in_norm[i]  = rsqrtf((float)max(in_cnt[i], 1));
  }
}

// ---------- exclusive scan of PADDED in-degrees (3-phase) ----------
// rows padded to multiple of 4 so agg1's gather loop needs no per-edge masking
__global__ void k_scan1(const int* __restrict__ deg, int* incl, int* partial) {
  __shared__ int s[SCAN_CH];
  int tid = threadIdx.x;
  int i = blockIdx.x * SCAN_CH + tid;
  int v = (i < N_NODES) ? ((deg[i] + 3) & ~3) : 0;
  s[tid] = v;
  for (int off = 1; off < SCAN_CH; off <<= 1) {
    __syncthreads();
    int x = (tid >= off) ? s[tid - off] : 0;
    __syncthreads();
    s[tid] += x;
  }
  __syncthreads();
  if (i < N_NODES) incl[i] = s[tid];
  if (tid == SCAN_CH - 1) partial[blockIdx.x] = s[tid];
}

__global__ void k_scan2(const int* __restrict__ partial, int* chunk_off, int* row_ptr) {
  if (threadIdx.x == 0 && blockIdx.x == 0) {
    int run = 0;
    for (int b = 0; b < NCH; b++) { chunk_off[b] = run; run += partial[b]; }
    row_ptr[N_NODES] = run;   // == padded edge count
  }
}

__global__ void k_scan3(const int* __restrict__ deg, const int* __restrict__ incl,
                        const int* __restrict__ chunk_off, int* row_ptr, int* cursor) {
  int i = blockIdx.x * SCAN_CH + threadIdx.x;
  if (i < N_NODES) {
    int dp = (deg[i] + 3) & ~3;
    int e = chunk_off[blockIdx.x] + incl[i] - dp;
    row_ptr[i] = e;
    cursor[i]  = e;
  }
}

// ---------- CSR fill (bucket by dst); padding slots filled by k_pad ----------
__global__ void k_fill(const int* __restrict__ src, const int* __restrict__ dst,
                       int* cursor, int* csr_src) {
  int e = blockIdx.x * 256 + threadIdx.x;
  if (e < N_EDGES) {
    int p = atomicAdd(&cursor[dst[e]], 1);
    csr_src[p] = src[e];
  }
}

// ---------- fill row-padding slots with the dummy (zero) source node ----------
__global__ void k_pad(const int* __restrict__ in_cnt, const int* __restrict__ row_ptr,
                      int* csr_src) {
  int i = blockIdx.x * 256 + threadIdx.x;
  if (i < N_NODES) {
    int d = in_cnt[i], dp = (d + 3) & ~3;
    int base = row_ptr[i];
    for (int j = d; j < dp; j++) csr_src[base + j] = DUMMY_SRC;
  }
}

// ---------- convert features, panel-major: xbp[p][n][64] = bf16(in_feat*out_norm) ----------
// rows >= N_NODES (incl. the dummy row 50000) are zero
__global__ void k_conv(const float* __restrict__ in_feat, const float* __restrict__ out_norm,
                       bf16_t* __restrict__ xbp) {
  int node = blockIdx.x, t = threadIdx.x;
  int p = t >> 4, fo = (t & 15) * 4;      // panel (16), feat offset within panel (64)
  bf16x4_t o;
  if (node < N_NODES) {
    float on = out_norm[node];
    float4 v = *(const float4*)(in_feat + (size_t)node * IN_DIM + p * PF + fo);
    o[0] = (bf16_t)(v.x * on); o[1] = (bf16_t)(v.y * on);
    o[2] = (bf16_t)(v.z * on); o[3] = (bf16_t)(v.w * on);
  } else {
    o[0] = (bf16_t)0.f; o[1] = (bf16_t)0.f; o[2] = (bf16_t)0.f; o[3] = (bf16_t)0.f;
  }
  *(bf16x4_t*)(xbp + (size_t)p * PSTRIDE + (size_t)node * PF + fo) = o;
}

// ---------- layer-1 aggregation: full-line gathers + XCD-pinned 6.4MB panels ----------
// r0 vs r2/r3 isolated the bottleneck as the L2 REQUEST path: r0's 512-feat panel
// had full-line requests but ~0% L2 hit (51MB panel); r2/r3's 32-feat panel hit L2
// 85% but with half-line scattered requests (2x count, ~5 TB/s effective). This
// version keeps BOTH: per-edge slice = 64 feats = 128B = one full line (8 lanes x
// 16B), wave-per-node (zero divergence), panel 6.4 MB XCD-pinned (~60% L2, rest L3).
__global__ void __launch_bounds__(256)
k_agg1(const bf16_t* __restrict__ xbp, const int* __restrict__ row_ptr,
       const int* __restrict__ csr_src, const float* __restrict__ in_norm,
       bf16_t* __restrict__ aggb) {
  int b = blockIdx.x;
  int xcd = b & (NXCD - 1), seq = b >> 3;
  int phase = seq / NGRP4, grp = seq - phase * NGRP4;
  int panel = xcd + (phase << 3);          // 0..15
  int wv = threadIdx.x >> 6, lane = threadIdx.x & 63;
  int sub = lane >> 3, fo = (lane & 7) << 3;   // edge slot (8), feat offset (x8)
  int node = grp * 4 + wv;                 // < M_PAD

  const bf16_t* xp = xbp + (size_t)panel * PSTRIDE + fo;

  int beg = 0, end = 0;
  if (node < N_NODES) { beg = row_ptr[node]; end = row_ptr[node + 1]; }

  float acc[8];
#pragma unroll
  for (int j = 0; j < 8; j++) acc[j] = 0.f;

  int e = beg;
  // 2-deep unroll: 2 idx loads + 2 line-gathers in flight per wave
  for (; e + 16 <= end; e += 16) {
    int s0 = __builtin_nontemporal_load(csr_src + e + sub);
    int s1 = __builtin_nontemporal_load(csr_src + e + 8 + sub);
    bf16x8_t v0 = *(const bf16x8_t*)(xp + ((size_t)(unsigned)s0 << 6));
    bf16x8_t v1 = *(const bf16x8_t*)(xp + ((size_t)(unsigned)s1 << 6));
#pragma unroll
    for (int j = 0; j < 8; j++) acc[j] += (float)v0[j];
#pragma unroll
    for (int j = 0; j < 8; j++) acc[j] += (float)v1[j];
  }
  if (e + 8 <= end) {
    int s0 = __builtin_nontemporal_load(csr_src + e + sub);
    bf16x8_t v0 = *(const bf16x8_t*)(xp + ((size_t)(unsigned)s0 << 6));
#pragma unroll
    for (int j = 0; j < 8; j++) acc[j] += (float)v0[j];
    e += 8;
  }
  if (e < end && sub < 4) {   // exactly 4 edges remain (rows padded to x4)
    int s0 = __builtin_nontemporal_load(csr_src + e + sub);
    bf16x8_t v0 = *(const bf16x8_t*)(xp + ((size_t)(unsigned)s0 << 6));
#pragma unroll
    for (int j = 0; j < 8; j++) acc[j] += (float)v0[j];
  }

  // reduce across the 8 edge-slots (lanes stride 8)
#pragma unroll
  for (int j = 0; j < 8; j++) {
    acc[j] += __shfl_xor(acc[j], 8);
    acc[j] += __shfl_xor(acc[j], 16);
    acc[j] += __shfl_xor(acc[j], 32);
  }

  if (sub == 0) {
    float inn = (node < N_NODES) ? in_norm[node] : 0.f;
    bf16x8_t o;
#pragma unroll
    for (int j = 0; j < 8; j++) o[j] = (bf16_t)(acc[j] * inn);
    __builtin_nontemporal_store(o,
        (bf16x8_t*)(aggb + (size_t)node * IN_DIM + panel * PF + fo));
  }
}

// ---------- W1 [K=1024][N=2048] fp32 -> W1t [N][K] bf16, LDS-tiled transpose ----------
__global__ void k_w1t(const float* __restrict__ W1, bf16_t* __restrict__ W1t) {
  __shared__ float tile[32][33];
  int k0 = blockIdx.x * 32, n0 = blockIdx.y * 32;
  int tx = threadIdx.x & 31, ty = threadIdx.x >> 5;   // 32 x 8
#pragma unroll
  for (int r = 0; r < 32; r += 8)
    tile[ty + r][tx] = W1[(size_t)(k0 + ty + r) * HID + n0 + tx];
  __syncthreads();
#pragma unroll
  for (int r = 0; r < 32; r += 8)
    W1t[(size_t)(n0 + ty + r) * IN_DIM + k0 + tx] = (bf16_t)tile[tx][ty + r];
}

// ---------- GEMM1: h1 = relu(agg @ W1 + b1) + fused BN column stats ----------
// m97 structure: 128x128 tile, BK=32, 4 waves in 2x2, 16x16x32 MFMA, global_load_lds w=16.
__global__ void __launch_bounds__(256)
k_gemm1(const bf16_t* __restrict__ A, const bf16_t* __restrict__ Bt,
        const float* __restrict__ b1, bf16_t* __restrict__ C,
        float* __restrict__ colsum, float* __restrict__ colsq) {
  __shared__ bf16_t As[128 * 32];
  __shared__ bf16_t Bs[128 * 32];
  int t = threadIdx.x;
  const int m0 = blockIdx.y * 128, n0 = blockIdx.x * 128;

  int lrow = t >> 2, lseg = t & 3;
  const bf16_t* aG0 = A + (size_t)(m0 + lrow) * IN_DIM + lseg * 8;
  const bf16_t* aG1 = aG0 + (size_t)64 * IN_DIM;
  const bf16_t* bG0 = Bt + (size_t)(n0 + lrow) * IN_DIM + lseg * 8;
  const bf16_t* bG1 = bG0 + (size_t)64 * IN_DIM;
  bf16_t* aL0 = As + t * 8; bf16_t* aL1 = As + 2048 + t * 8;
  bf16_t* bL0 = Bs + t * 8; bf16_t* bL1 = Bs + 2048 + t * 8;

  int wv = t >> 6, ln = t & 63;
  int wm = (wv >> 1) * 64, wn = (wv & 1) * 64;
  int fr = ln & 15, fq = ln >> 4;
  const bf16_t* aF = As + (wm + fr) * 32 + fq * 8;
  const bf16_t* bF = Bs + (wn + fr) * 32 + fq * 8;

  f32x4_t acc[4][4];
#pragma unroll
  for (int i = 0; i < 4; i++)
#pragma unroll
    for (int j = 0; j < 4; j++) { acc[i][j][0]=0.f; acc[i][j][1]=0.f; acc[i][j][2]=0.f; acc[i][j][3]=0.f; }

  for (int kt = 0; kt < IN_DIM; kt += 32) {
    __syncthreads();
    gl2lds16(aG0 + kt, aL0);
    gl2lds16(aG1 + kt, aL1);
    gl2lds16(bG0 + kt, bL0);
    gl2lds16(bG1 + kt, bL1);
    __syncthreads();
    bf16x8_t af[4], bfr[4];
#pragma unroll
    for (int i = 0; i < 4; i++) af[i]  = *(const bf16x8_t*)(aF + i * 16 * 32);
#pragma unroll
    for (int j = 0; j < 4; j++) bfr[j] = *(const bf16x8_t*)(bF + j * 16 * 32);
#pragma unroll
    for (int i = 0; i < 4; i++)
#pragma unroll
      for (int j = 0; j < 4; j++)
        acc[i][j] = __builtin_amdgcn_mfma_f32_16x16x32_bf16(af[i], bfr[j], acc[i][j], 0, 0, 0);
  }

#pragma unroll
  for (int j = 0; j < 4; j++) {
    int col = n0 + wn + j * 16 + fr;
    float bias = b1[col];
    float s = 0.f, ss = 0.f;
#pragma unroll
    for (int i = 0; i < 4; i++) {
#pragma unroll
      for (int r = 0; r < 4; r++) {
        int row = m0 + wm + i * 16 + fq * 4 + r;
        float v = acc[i][j][r] + bias;
        v = v > 0.f ? v : 0.f;
        bf16_t bv = (bf16_t)v;
        __builtin_nontemporal_store(*(short*)&bv, (short*)&C[(size_t)row * HID + col]);
        if (row < N_NODES) { s += v; ss += v * v; }
      }
    }
    s  += __shfl_xor(s, 16);  s  += __shfl_xor(s, 32);
    ss += __shfl_xor(ss, 16); ss += __shfl_xor(ss, 32);
    if (fq == 0) {
      atomicAdd(&colsum[col], s);
      atomicAdd(&colsq[col], ss);
    }
  }
}

// ---------- fold BN into Wout: cw[f,o] = rs[f]*Wout[f,o]; mrs[f] = mean[f]*rs[f] ----------
__global__ void k_bnfin(const float* __restrict__ colsum, const float* __restrict__ colsq,
                        const float* __restrict__ Wout,
                        float* cw0, float* cw1, float* cw2, float* mrs) {
  int f = blockIdx.x * 256 + threadIdx.x;
  if (f < HID) {
    float mean = colsum[f] * (1.f / N_NODES);
    float var  = colsq[f] * (1.f / N_NODES) - mean * mean;
    float rs   = rsqrtf(var + BN_EPS);
    cw0[f] = rs * Wout[f * 3 + 0];
    cw1[f] = rs * Wout[f * 3 + 1];
    cw2[f] = rs * Wout[f * 3 + 2];
    mrs[f] = mean * rs;
  }
}

// ---------- ct[o] = sum_f mrs[f]*Wout[f,o] ----------
__global__ void k_ct(const float* __restrict__ mrs, const float* __restrict__ Wout, float* ct) {
  __shared__ float red[3][256];
  int tid = threadIdx.x;
  float s0 = 0.f, s1 = 0.f, s2 = 0.f;
  for (int f = tid; f < HID; f += 256) {
    float m = mrs[f];
    s0 += m * Wout[f * 3 + 0];
    s1 += m * Wout[f * 3 + 1];
    s2 += m * Wout[f * 3 + 2];
  }
  red[0][tid] = s0; red[1][tid] = s1; red[2][tid] = s2;
  __syncthreads();
  for (int off = 128; off; off >>= 1) {
    if (tid < off) {
      red[0][tid] += red[0][tid + off];
      red[1][tid] += red[1][tid + off];
      red[2][tid] += red[2][tid + off];
    }
    __syncthreads();
  }
  if (tid == 0) { ct[0] = red[0][0]; ct[1] = red[1][0]; ct[2] = red[2][0]; }
}

// ---------- t[n] = out_norm[n] * (h_bn[n] @ Wout) via cw/ct ----------
__global__ void k_tmat(const bf16_t* __restrict__ h1, const float* __restrict__ cw0,
                       const float* __restrict__ cw1, const float* __restrict__ cw2,
                       const float* __restrict__ ct, const float* __restrict__ out_norm,
                       float4* __restrict__ t4) {
  int n = blockIdx.x, tid = threadIdx.x;
  int f0 = tid * 8;
  bf16x8_t hv = *(const bf16x8_t*)(h1 + (size_t)n * HID + f0);
  float s0 = 0.f, s1 = 0.f, s2 = 0.f;
#pragma unroll
  for (int j = 0; j < 8; j++) {
    float h = (float)hv[j];
    s0 += h * cw0[f0 + j];
    s1 += h * cw1[f0 + j];
    s2 += h * cw2[f0 + j];
  }
#pragma unroll
  for (int off = 32; off; off >>= 1) {
    s0 += __shfl_down(s0, off);
    s1 += __shfl_down(s1, off);
    s2 += __shfl_down(s2, off);
  }
  __shared__ float red[3][4];
  int wv = tid >> 6, ln = tid & 63;
  if (ln == 0) { red[0][wv] = s0; red[1][wv] = s1; red[2][wv] = s2; }
  __syncthreads();
  if (tid == 0) {
    float r0 = red[0][0] + red[0][1] + red[0][2] + red[0][3];
    float r1 = red[1][0] + red[1][1] + red[1][2] + red[1][3];
    float r2 = red[2][0] + red[2][1] + red[2][2] + red[2][3];
    float on = out_norm[n];
    t4[n] = make_float4(on * (r0 - ct[0]), on * (r1 - ct[1]), on * (r2 - ct[2]), 0.f);
  }
}

// ---------- layer-2 aggregation (3 feats) + bias + softmax ----------
// padded CSR slots point at t4[DUMMY_SRC] which is zeroed
__global__ void k_out(const int* __restrict__ row_ptr, const int* __restrict__ csr_src,
                      const float4* __restrict__ t4, const float* __restrict__ in_norm,
                      const float* __restrict__ bout, float* __restrict__ out) {
  int i = blockIdx.x * 256 + threadIdx.x;
  if (i >= N_NODES) return;
  float a0 = 0.f, a1 = 0.f, a2 = 0.f;
  int beg = row_ptr[i], end = row_ptr[i + 1];
  for (int e = beg; e < end; e++) {
    float4 tv = t4[csr_src[e]];
    a0 += tv.x; a1 += tv.y; a2 += tv.z;
  }
  float inn = in_norm[i];
  float l0 = inn * a0 + bout[0];
  float l1 = inn * a1 + bout[1];
  float l2 = inn * a2 + bout[2];
  float m = fmaxf(l0, fmaxf(l1, l2));
  float e0 = expf(l0 - m), e1 = expf(l1 - m), e2 = expf(l2 - m);
  float rs = 1.f / (e0 + e1 + e2);
  out[i * 3 + 0] = e0 * rs;
  out[i * 3 + 1] = e1 * rs;
  out[i * 3 + 2] = e2 * rs;
}

extern "C" void kernel_launch(void* const* d_in, const int* in_sizes, int n_in,
                              void* d_out, int out_size, void* d_ws, size_t ws_size,
                              hipStream_t stream) {
  const float* in_feat = (const float*)d_in[0];
  const int*   src     = (const int*)d_in[1];
  const int*   dst     = (const int*)d_in[2];
  const float* W1      = (const float*)d_in[3];
  const float* b1      = (const float*)d_in[4];
  const float* Wout    = (const float*)d_in[5];
  const float* bout    = (const float*)d_in[6];
  float* out = (float*)d_out;

  char* p = (char*)d_ws;
  auto alloc = [&](size_t bytes) { char* r = p; p += (bytes + 255) & ~(size_t)255; return r; };
  bf16_t* h1      = (bf16_t*)alloc((size_t)M_PAD * HID * 2);      // 205 MB
  bf16_t* aggb    = (bf16_t*)alloc((size_t)M_PAD * IN_DIM * 2);   // 102.5 MB
  bf16_t* xbp     = (bf16_t*)alloc((size_t)NPAN * PSTRIDE * 2);   // 102.5 MB, panel-major
  bf16_t* W1t     = (bf16_t*)alloc((size_t)HID * IN_DIM * 2);     // 4 MB
  int* csr_src    = (int*)alloc((size_t)E_PAD_MAX * 4);           // 7 MB (padded + slack)
  int* row_ptr    = (int*)alloc((size_t)(N_NODES + 1) * 4);
  int* cursor     = (int*)alloc((size_t)N_NODES * 4);
  int* incl       = (int*)alloc((size_t)N_NODES * 4);
  int* partial    = (int*)alloc((size_t)NCH * 4);
  int* chunk_off  = (int*)alloc((size_t)NCH * 4);
  int* out_cnt    = (int*)alloc((size_t)N_NODES * 4);
  int* in_cnt     = (int*)alloc((size_t)N_NODES * 4);
  float* out_norm = (float*)alloc((size_t)N_NODES * 4);
  float* in_norm  = (float*)alloc((size_t)N_NODES * 4);
  float* colsum   = (float*)alloc((size_t)HID * 4);
  float* colsq    = (float*)alloc((size_t)HID * 4);
  float* cw0      = (float*)alloc((size_t)HID * 4);
  float* cw1      = (float*)alloc((size_t)HID * 4);
  float* cw2      = (float*)alloc((size_t)HID * 4);
  float* mrs      = (float*)alloc((size_t)HID * 4);
  float* ct       = (float*)alloc(4 * 4);
  float4* t4      = (float4*)alloc((size_t)M_PAD * 16);

  // ws is poisoned 0xAA each call — zero what needs zeroing
  hipMemsetAsync(out_cnt, 0, (size_t)N_NODES * 4, stream);
  hipMemsetAsync(in_cnt,  0, (size_t)N_NODES * 4, stream);
  hipMemsetAsync(colsum,  0, (size_t)HID * 4, stream);
  hipMemsetAsync(colsq,   0, (size_t)HID * 4, stream);
  hipMemsetAsync(t4 + N_NODES, 0, (size_t)(M_PAD - N_NODES) * 16, stream); // dummy t4 rows

  k_hist <<<(N_EDGES + 255) / 256, 256, 0, stream>>>(src, dst, out_cnt, in_cnt);
  k_norms<<<(N_NODES + 255) / 256, 256, 0, stream>>>(out_cnt, in_cnt, out_norm, in_norm);
  k_conv <<<M_PAD, 256, 0, stream>>>(in_feat, out_norm, xbp);
  k_scan1<<<NCH, SCAN_CH, 0, stream>>>(in_cnt, incl, partial);
  k_scan2<<<1, 64, 0, stream>>>(partial, chunk_off, row_ptr);
  k_scan3<<<NCH, SCAN_CH, 0, stream>>>(in_cnt, incl, chunk_off, row_ptr, cursor);
  k_pad  <<<(N_NODES + 255) / 256, 256, 0, stream>>>(in_cnt, row_ptr, csr_src);
  k_fill <<<(N_EDGES + 255) / 256, 256, 0, stream>>>(src, dst, cursor, csr_src);
  k_w1t  <<<dim3(IN_DIM / 32, HID / 32), 256, 0, stream>>>(W1, W1t);
  k_agg1 <<<NXCD * (NPAN / NXCD) * NGRP4, 256, 0, stream>>>(xbp, row_ptr, csr_src, in_norm, aggb);
  k_gemm1<<<dim3(HID / 128, M_PAD / 128), 256, 0, stream>>>(aggb, W1t, b1, h1, colsum, colsq);
  k_bnfin<<<HID / 256, 256, 0, stream>>>(colsum, colsq, Wout, cw0, cw1, cw2, mrs);
  k_ct   <<<1, 256, 0, stream>>>(mrs, Wout, ct);
  k_tmat <<<N_NODES, 256, 0, stream>>>(h1, cw0, cw1, cw2, ct, out_norm, t4);
  k_out  <<<(N_NODES + 255) / 256, 256, 0, stream>>>(row_ptr, csr_src, t4, in_norm, bout, out);
}